// Round 4
// baseline (603.876 us; speedup 1.0000x reference)
//
#include <hip/hip_runtime.h>
#include <cstdint>
#include <cstddef>

#define T_TOK 8192
#define C_DIM 2048
#define H_HEADS 8
#define D_HEAD 256

typedef __bf16 v8bf __attribute__((ext_vector_type(8)));
typedef float v4f __attribute__((ext_vector_type(4)));
typedef float v8f __attribute__((ext_vector_type(8)));

// Async global->LDS 16B copy. LDS dest semantics: wave-uniform base + lane*16.
__device__ __forceinline__ void async_load16(const void* gptr, void* lptr) {
    auto g = reinterpret_cast<__attribute__((address_space(1))) void*>(
        reinterpret_cast<uintptr_t>(gptr));
    auto l = reinterpret_cast<__attribute__((address_space(3))) void*>(
        static_cast<uint32_t>(reinterpret_cast<uintptr_t>(lptr)));
    __builtin_amdgcn_global_load_lds(g, l, 16, 0, 0);
}

// fp32 -> bf16, 8 elements per thread.
__global__ __launch_bounds__(256) void cvt_kernel(
    const float* __restrict__ in, __bf16* __restrict__ out)
{
    const size_t i = ((size_t)blockIdx.x * 256 + threadIdx.x) * 8;
    v8f f = *(const v8f*)&in[i];
    v8bf b;
#pragma unroll
    for (int j = 0; j < 8; ++j) b[j] = (__bf16)f[j];
    *(v8bf*)&out[i] = b;
}

// C[m,n] = sum_k A[m,k]*B[n,k] + bias[n] (+ residual[m,n]); A,B bf16, fp32 accum.
// 256x256 tile, 512 threads (8 waves, 2x4 grid, 128x64 out per wave), 16x16x32
// MFMA (the empirically conflict-free family; 32x32 measured 1.26e7 conflicts).
//
// Ring-4 K-half pipeline (8-phase-template port, no sched_barrier pins):
//   K split into NH = K/32 half-tiles; slot(h) = h&3; 4 slots x 32KB = 128KB.
//   Compute half h (2 phases x 16 MFMA) while halves h+1..h+3 are in flight.
//   Phase = { ds_read_b128 frags | 2 global_load_lds of half h+3 | barrier |
//             lgkmcnt(0) | setprio(1) 16xMFMA setprio(0) | barrier }.
//   Boundary: counted vmcnt(8) once per half (drains h+1 only; h+2,h+3 stay in
//   flight -> never drains to 0 in steady state). Tail: vmcnt 8->4->0.
//   Race-free: staging targets slot (h-1)&3 whose readers all finished before
//   the previous boundary barrier.
// Rotation swizzle (4 chunks/row-half): stage source chunk c=((tid&3)-(tid>>2))&3
// with linear LDS dest; frag read at phys chunk (quad+r)&3.
// XCD swizzle: each XCD owns an n-slab; requires (N/256) % 8 == 0.
template <typename OutT>
__global__ __launch_bounds__(512, 2) void gemm256_kernel(
    const __bf16* __restrict__ A, const __bf16* __restrict__ B,
    const float* __restrict__ bias, const float* __restrict__ residual,
    OutT* __restrict__ Cmat, int M, int N, int K)
{
    __shared__ __align__(16) __bf16 lds[4 * 16384];  // 4 slots x (A 8192 | B 8192) elems

    const int tid  = threadIdx.x;
    const int wave = tid >> 6;
    const int lane = tid & 63;
    const int lane_m = lane & 15;      // MFMA row/col within 16-tile
    const int quad   = lane >> 4;      // MFMA k-group: k = quad*8 + j

    const int nbm = M >> 8;
    const int nbn = N >> 8;
    const int npx = nbn >> 3;          // n-blocks per XCD
    const int bb   = blockIdx.x;
    const int xcd  = bb & 7;
    const int slot = bb >> 3;
    const int n_blk = xcd * npx + slot / nbm;
    const int m_blk = slot % nbm;
    const int block_m = m_blk << 8;
    const int block_n = n_blk << 8;

    const int wave_m = wave >> 2;      // 0..1 -> 128-row half
    const int wave_n = wave & 3;       // 0..3 -> 64-col slab

    // Staging: chunk id = l*512 + tid -> row = l*128 + (tid>>2), p = tid&3,
    // rotated source chunk c = (p - row)&3 = ((tid&3)-(tid>>2))&3 (l-indep).
    const int srow4 = tid >> 2;
    const int crot  = ((tid & 3) - (tid >> 2)) & 3;
    const __bf16* aS = &A[(size_t)(block_m + srow4) * K + crot * 8];
    const __bf16* bS = &B[(size_t)(block_n + srow4) * K + crot * 8];
    const int dstW = wave * 512;       // wave-uniform dest base (elems), l=0

    // stg: one (A,B) load pair (l = 0 or 1) of global half h into slot s.
    auto stg = [&](int s, int h, int l) {
        const size_t go = (size_t)l * 128 * K + (size_t)h * 32;
        async_load16(aS + go, &lds[s * 16384 +        l * 4096 + dstW]);
        async_load16(bS + go, &lds[s * 16384 + 8192 + l * 4096 + dstW]);
    };

    // Per-lane fragment offsets within a slot (elems).
    int aOff[8], bOff[4];
#pragma unroll
    for (int i = 0; i < 8; ++i) {
        const int r = wave_m * 128 + i * 16 + lane_m;
        aOff[i] = r * 32 + ((quad + r) & 3) * 8;
    }
#pragma unroll
    for (int j = 0; j < 4; ++j) {
        const int r = wave_n * 64 + j * 16 + lane_m;
        bOff[j] = 8192 + r * 32 + ((quad + r) & 3) * 8;
    }

    v4f acc[8][4];
#pragma unroll
    for (int i = 0; i < 8; ++i)
#pragma unroll
        for (int j = 0; j < 4; ++j) {
            acc[i][j][0] = 0.f; acc[i][j][1] = 0.f;
            acc[i][j][2] = 0.f; acc[i][j][3] = 0.f;
        }

    const int NH = K >> 5;             // K-halves (64 for K=2048)
    // Prologue: halves 0,1,2 staged (12 loads); drain half 0 only.
    stg(0, 0, 0); stg(0, 0, 1);
    stg(1, 1, 0); stg(1, 1, 1);
    stg(2, 2, 0); stg(2, 2, 1);
    asm volatile("s_waitcnt vmcnt(8)" ::: "memory");
    __builtin_amdgcn_s_barrier();

    for (int h = 0; h < NH; ++h) {
        const int sb = (h & 3) * 16384;      // current slot base
        const int sp = (h + 3) & 3;          // stage-target slot
        const bool do_stage = (h + 3 < NH);
        v8bf bfr[4], af[4], af2[4];

        // ---- phase A: read B j0-3 + A i0-3 (8 reads); stage pair l=0 -------
#pragma unroll
        for (int j = 0; j < 4; ++j)
            bfr[j] = *(const v8bf*)&lds[sb + bOff[j]];
#pragma unroll
        for (int i = 0; i < 4; ++i)
            af[i] = *(const v8bf*)&lds[sb + aOff[i]];
        if (do_stage) stg(sp, h + 3, 0);
        __builtin_amdgcn_s_barrier();
        asm volatile("s_waitcnt lgkmcnt(0)" ::: "memory");
        __builtin_amdgcn_s_setprio(1);
#pragma unroll
        for (int i = 0; i < 4; ++i)
#pragma unroll
            for (int j = 0; j < 4; ++j)
                acc[i][j] = __builtin_amdgcn_mfma_f32_16x16x32_bf16(
                    af[i], bfr[j], acc[i][j], 0, 0, 0);
        __builtin_amdgcn_s_setprio(0);
        __builtin_amdgcn_s_barrier();

        // ---- phase B: read A i4-7 (4 reads); stage pair l=1 ----------------
#pragma unroll
        for (int i = 0; i < 4; ++i)
            af2[i] = *(const v8bf*)&lds[sb + aOff[4 + i]];
        if (do_stage) stg(sp, h + 3, 1);
        __builtin_amdgcn_s_barrier();
        asm volatile("s_waitcnt lgkmcnt(0)" ::: "memory");
        __builtin_amdgcn_s_setprio(1);
#pragma unroll
        for (int i = 0; i < 4; ++i)
#pragma unroll
            for (int j = 0; j < 4; ++j)
                acc[4 + i][j] = __builtin_amdgcn_mfma_f32_16x16x32_bf16(
                    af2[i], bfr[j], acc[4 + i][j], 0, 0, 0);
        __builtin_amdgcn_s_setprio(0);

        // ---- boundary: drain half h+1 only; keep h+2,h+3 in flight ---------
        if (h < NH - 1) {
            if (h + 3 < NH) {
                asm volatile("s_waitcnt vmcnt(8)" ::: "memory");
            } else if (h + 2 < NH) {
                asm volatile("s_waitcnt vmcnt(4)" ::: "memory");
            } else {
                asm volatile("s_waitcnt vmcnt(0)" ::: "memory");
            }
            __builtin_amdgcn_s_barrier();
        }
    }

    // Epilogue. C/D layout: col = lane&15, row = quad*4 + reg  [verified m89]
#pragma unroll
    for (int i = 0; i < 8; ++i) {
        const int row0 = block_m + wave_m * 128 + i * 16 + quad * 4;
#pragma unroll
        for (int j = 0; j < 4; ++j) {
            const int col = block_n + wave_n * 64 + j * 16 + lane_m;
            const float bv = bias[col];
#pragma unroll
            for (int r = 0; r < 4; ++r) {
                float val = acc[i][j][r] + bv;
                const size_t off = (size_t)(row0 + r) * N + col;
                if (residual) val += residual[off];
                Cmat[off] = (OutT)val;
            }
        }
    }
}

// Per-token 8x8 attention: one wave per token, 4 tokens per 256-thread block.
// q/out stride 2048; k,v packed in kv with token stride 4096 (k at +0, v at +2048).
// out may alias q (q reads are value-dependencies of the stores).
__global__ __launch_bounds__(256) void attn_kernel(
    const __bf16* __restrict__ q, const __bf16* __restrict__ kv,
    __bf16* __restrict__ out)
{
    __shared__ __align__(16) __bf16 sq[4 * 2048];
    __shared__ __align__(16) __bf16 sk[4 * 2048];
    __shared__ __align__(16) __bf16 sv[4 * 2048];

    const int wave = threadIdx.x >> 6;
    const int lane = threadIdx.x & 63;
    const int t = blockIdx.x * 4 + wave;

    const __bf16* qt = q + (size_t)t * C_DIM;
    const __bf16* kt = kv + (size_t)t * 2 * C_DIM;
    const __bf16* vt = kt + C_DIM;
    __bf16* sqw = &sq[wave * C_DIM];
    __bf16* skw = &sk[wave * C_DIM];
    __bf16* svw = &sv[wave * C_DIM];

#pragma unroll
    for (int p = 0; p < 4; ++p) {
        const int idx = (p * 64 + lane) * 8;
        *(v8bf*)&sqw[idx] = *(const v8bf*)&qt[idx];
        *(v8bf*)&skw[idx] = *(const v8bf*)&kt[idx];
        *(v8bf*)&svw[idx] = *(const v8bf*)&vt[idx];
    }
    // all LDS traffic is wave-local: no __syncthreads needed

    const int h = lane >> 3;
    const int g = lane & 7;
    float s = 0.f;
#pragma unroll 4
    for (int d = 0; d < D_HEAD; d += 8) {
        v8bf qa = *(const v8bf*)&sqw[h * D_HEAD + d];
        v8bf ka = *(const v8bf*)&skw[g * D_HEAD + d];
#pragma unroll
        for (int jj = 0; jj < 8; ++jj) s += (float)qa[jj] * (float)ka[jj];
    }
    s *= 0.0625f;  // D^-0.5 = 1/16

    float m = s;
    m = fmaxf(m, __shfl_xor(m, 1));
    m = fmaxf(m, __shfl_xor(m, 2));
    m = fmaxf(m, __shfl_xor(m, 4));
    const float e = __expf(s - m);
    float dsum = e;
    dsum += __shfl_xor(dsum, 1);
    dsum += __shfl_xor(dsum, 2);
    dsum += __shfl_xor(dsum, 4);
    const float p_attn = e / dsum;

    float attnv[8];
#pragma unroll
    for (int gg = 0; gg < 8; ++gg)
        attnv[gg] = __shfl(p_attn, (lane & 56) | gg);

    __bf16* outp = out + (size_t)t * C_DIM + h * D_HEAD + g * 32;
    const __bf16* vbase = &svw[g * 32];
#pragma unroll
    for (int dd = 0; dd < 32; dd += 8) {
        float o[8] = {0.f, 0.f, 0.f, 0.f, 0.f, 0.f, 0.f, 0.f};
#pragma unroll
        for (int gg = 0; gg < 8; ++gg) {
            v8bf vv = *(const v8bf*)&vbase[gg * D_HEAD + dd];
            const float pg = attnv[gg];
#pragma unroll
            for (int jj = 0; jj < 8; ++jj) o[jj] += pg * (float)vv[jj];
        }
        v8bf ov;
#pragma unroll
        for (int jj = 0; jj < 8; ++jj) ov[jj] = (__bf16)o[jj];
        *(v8bf*)&outp[dd] = ov;
    }
}

extern "C" void kernel_launch(void* const* d_in, const int* in_sizes, int n_in,
                              void* d_out, int out_size, void* d_ws, size_t ws_size,
                              hipStream_t stream) {
    const float* x  = (const float*)d_in[0];
    const float* y  = (const float*)d_in[1];
    const float* Wq = (const float*)d_in[2];
    const float* bq = (const float*)d_in[3];
    const float* Wk = (const float*)d_in[4];
    const float* bk = (const float*)d_in[5];
    const float* Wv = (const float*)d_in[6];
    const float* bv = (const float*)d_in[7];
    const float* Wo = (const float*)d_in[8];
    const float* bo = (const float*)d_in[9];
    float* out = (float*)d_out;  // fp32 output

    const size_t TC = (size_t)T_TOK * C_DIM;   // 16,777,216
    const size_t CC = (size_t)C_DIM * C_DIM;   //  4,194,304

    // bf16 workspace, 4*TC + 2*CC elems (~151 MB) + 16 KB fp32 bias:
    //   [xb TC][ext TC][yb TC][q TC][Wb 2CC][bias_kv 4096 f32]
    // kv_ws overlays xb+ext (xb dead after Q-GEMM; stream order serializes).
    __bf16* xb    = (__bf16*)d_ws;
    __bf16* kv_ws = xb;                 // 2*TC, written after xb is dead
    __bf16* yb    = xb + 2 * TC;
    __bf16* q_ws  = yb + TC;
    __bf16* Wb    = q_ws + TC;          // 2*CC slot, reused sequentially
    float*  bias_kv = (float*)(Wb + 2 * CC);
    __bf16* a_ws  = q_ws;               // attn overwrites q in place

    dim3 cblock(256), gblock(512);
    const dim3 cvtTC(TC / (8 * 256)), cvtCC(CC / (8 * 256));

    cvt_kernel<<<cvtTC, cblock, 0, stream>>>(x, xb);
    cvt_kernel<<<cvtTC, cblock, 0, stream>>>(y, yb);
    hipMemcpyAsync(bias_kv,        bk, C_DIM * sizeof(float),
                   hipMemcpyDeviceToDevice, stream);
    hipMemcpyAsync(bias_kv + C_DIM, bv, C_DIM * sizeof(float),
                   hipMemcpyDeviceToDevice, stream);

    // Q = x @ Wq^T + bq
    cvt_kernel<<<cvtCC, cblock, 0, stream>>>(Wq, Wb);
    gemm256_kernel<__bf16><<<dim3((T_TOK/256)*(C_DIM/256)), gblock, 0, stream>>>(
        xb, Wb, bq, nullptr, q_ws, T_TOK, C_DIM, C_DIM);

    // [K|V] = y @ [Wk;Wv]^T + [bk;bv]   (N = 4096, overlays xb+ext)
    cvt_kernel<<<cvtCC, cblock, 0, stream>>>(Wk, Wb);
    cvt_kernel<<<cvtCC, cblock, 0, stream>>>(Wv, Wb + CC);
    gemm256_kernel<__bf16><<<dim3((T_TOK/256)*(2*C_DIM/256)), gblock, 0, stream>>>(
        yb, Wb, bias_kv, nullptr, kv_ws, T_TOK, 2 * C_DIM, C_DIM);

    attn_kernel<<<dim3(T_TOK / 4), cblock, 0, stream>>>(q_ws, kv_ws, a_ws);

    // out = attn @ Wo^T + bo + x
    cvt_kernel<<<cvtCC, cblock, 0, stream>>>(Wo, Wb);
    gemm256_kernel<float><<<dim3((T_TOK/256)*(C_DIM/256)), gblock, 0, stream>>>(
        a_ws, Wb, bo, x, out, T_TOK, C_DIM, C_DIM);
}